// Round 3
// baseline (477.504 us; speedup 1.0000x reference)
//
#include <hip/hip_runtime.h>
#include <math.h>

#define T_   50
#define B_   2048
#define NS_  12
#define NC_  4
#define NSC_ 16
#define LDC  20     // padded LDS row stride for 16-wide matrices
#define AST  808    // per-alpha stride for tau trajectories (50*16=800, +8 bank skew)

__device__ __forceinline__ float dot4f(const float4 a, const float4 b) {
    return a.x*b.x + a.y*b.y + a.z*b.z + a.w*b.w;
}
__device__ __forceinline__ void axpy4(float4& acc, float s, const float4 v) {
    acc.x += s*v.x; acc.y += s*v.y; acc.z += s*v.z; acc.w += s*v.w;
}

// Wave-local sync for single-wave blocks: orders LDS write->read (lgkmcnt(0))
// WITHOUT draining vmcnt, so global prefetch loads stay in flight.
// 0xC07F = vmcnt(63) expcnt(7) lgkmcnt(0).
__device__ __forceinline__ void wsync() {
    __builtin_amdgcn_wave_barrier();
    __builtin_amdgcn_s_waitcnt(0xC07F);
    __builtin_amdgcn_wave_barrier();
}

// ---------------------------------------------------------------------------
// Kernel 1: backward Riccati recursion. One wave per batch element.
// DS-reduced: V rows read as b128, C never staged (register-carried into Q),
// q merged into Q phase (reuses F-column scalars).
// ---------------------------------------------------------------------------
struct RicPref { float4 rC, rAux; };

__device__ __forceinline__ RicPref ric_load(
    const float* Cg, const float* cg, const float* Fg, const float* fg,
    int t, int b, int lane)
{
    RicPref p;
    const size_t base = (size_t)t * B_ + b;
    p.rC = ((const float4*)(Cg + base*256))[lane];   // row lane>>2, chunk lane&3
    if (lane < 48)      p.rAux = ((const float4*)(Fg + base*192))[lane];
    else if (lane < 52) p.rAux = ((const float4*)(cg + base*16))[lane-48];
    else if (lane < 55) p.rAux = ((const float4*)(fg + base*12))[lane-52];
    return p;
}

__global__ __launch_bounds__(64) void riccati_kernel(
    const float* __restrict__ Cg, const float* __restrict__ cg,
    const float* __restrict__ Fg, const float* __restrict__ fg,
    float* __restrict__ Kk)
{
    const int b    = blockIdx.x;
    const int lane = threadIdx.x;

    __shared__ __align__(16) float sV[144];      // V 12x12 (stride 12, rows 48B-aligned)
    __shared__ __align__(16) float sv[12];
    __shared__ __align__(16) float sF[12*LDC];   // F 12x16 (stride 20)
    __shared__ __align__(16) float sc[16];
    __shared__ __align__(16) float sf[12];
    __shared__ __align__(16) float sP[12*LDC];   // P = V*F
    __shared__ __align__(16) float sQ[16*LDC];   // Q 16x16
    __shared__ __align__(16) float sq[16];
    __shared__ __align__(16) float stmp[12];     // V f + v
    __shared__ __align__(16) float sK[48];       // K 4x12 row-major
    __shared__ __align__(16) float skk[4];
    __shared__ __align__(16) float sM[144];      // M = K^T Qux (stride 12)

    for (int i = lane; i < 144; i += 64) sV[i] = 0.f;
    if (lane < 12) sv[lane] = 0.f;

    RicPref cur = ric_load(Cg, cg, Fg, fg, T_-1, b, lane);
    wsync();

    for (int t = T_ - 1; t >= 0; --t) {
        const size_t base = (size_t)t * B_ + b;

        // ---- stage F, c, f from prefetch regs (C stays in registers) ----
        wsync();   // WAR vs prior step's readers of sF/sc/sf
        const float4 rCq = cur.rC;   // consumed in Q phase
        {
            const int row = lane >> 2, ch = (lane & 3) << 2;
            if (lane < 48)      *(float4*)(sF + row*LDC + ch) = cur.rAux;
            else if (lane < 52) ((float4*)sc)[lane-48] = cur.rAux;
            else if (lane < 55) ((float4*)sf)[lane-52] = cur.rAux;
        }
        RicPref nxt = ric_load(Cg, cg, Fg, fg, (t > 0) ? t-1 : 0, b, lane);
        wsync();

        // ---- P = V * F (12x16); tmp = V f + v (merged into jc==0 lanes) ----
        if (lane < 48) {
            const int k = lane >> 2, jc = (lane & 3) << 2;
            const float4 v0 = *(const float4*)(sV + k*12);
            const float4 v1 = *(const float4*)(sV + k*12 + 4);
            const float4 v2 = *(const float4*)(sV + k*12 + 8);
            const float vk[12] = {v0.x,v0.y,v0.z,v0.w, v1.x,v1.y,v1.z,v1.w,
                                  v2.x,v2.y,v2.z,v2.w};
            float4 acc = make_float4(0.f,0.f,0.f,0.f);
            #pragma unroll
            for (int l = 0; l < 12; ++l) {
                axpy4(acc, vk[l], *(const float4*)(sF + l*LDC + jc));
            }
            *(float4*)(sP + k*LDC + jc) = acc;
            if (jc == 0) {
                float accT = sv[k];
                #pragma unroll
                for (int l = 0; l < 12; ++l) accT += vk[l] * sf[l];
                stmp[k] = accT;
            }
        }
        wsync();

        // ---- Q = C + F^T P; q = c + F^T tmp (merged, reuses F column) ----
        {
            const int i = lane >> 2, jc = (lane & 3) << 2;
            float4 acc = rCq;
            float fcol[12];
            #pragma unroll
            for (int k = 0; k < 12; ++k) {
                fcol[k] = sF[k*LDC + i];
                axpy4(acc, fcol[k], *(const float4*)(sP + k*LDC + jc));
            }
            *(float4*)(sQ + i*LDC + jc) = acc;
            if (jc == 0) {
                float accq = sc[i];
                #pragma unroll
                for (int k = 0; k < 12; ++k) accq += fcol[k] * stmp[k];
                sq[i] = accq;
            }
        }
        wsync();

        // ---- solve Quu * sol = [Qux | qu] via redundant 4x4 Cholesky ----
        {
            const float* Qu = sQ + 12*LDC + 12;
            const float a00=Qu[0],      a01=Qu[1],      a02=Qu[2],      a03=Qu[3];
            const float a11=Qu[LDC+1],  a12=Qu[LDC+2],  a13=Qu[LDC+3];
            const float a22=Qu[2*LDC+2],a23=Qu[2*LDC+3],a33=Qu[3*LDC+3];
            const float l00 = sqrtf(a00), i00 = 1.f/l00;
            const float l10 = a01*i00, l20 = a02*i00, l30 = a03*i00;
            const float l11 = sqrtf(a11 - l10*l10), i11 = 1.f/l11;
            const float l21 = (a12 - l20*l10)*i11;
            const float l31 = (a13 - l30*l10)*i11;
            const float l22 = sqrtf(a22 - l20*l20 - l21*l21), i22 = 1.f/l22;
            const float l32 = (a23 - l30*l20 - l31*l21)*i22;
            const float l33 = sqrtf(a33 - l30*l30 - l31*l31 - l32*l32), i33 = 1.f/l33;
            if (lane < 13) {
                float r0, r1, r2, r3;
                if (lane < 12) {
                    r0 = sQ[12*LDC + lane]; r1 = sQ[13*LDC + lane];
                    r2 = sQ[14*LDC + lane]; r3 = sQ[15*LDC + lane];
                } else {
                    r0 = sq[12]; r1 = sq[13]; r2 = sq[14]; r3 = sq[15];
                }
                const float y0 = r0*i00;
                const float y1 = (r1 - l10*y0)*i11;
                const float y2 = (r2 - l20*y0 - l21*y1)*i22;
                const float y3 = (r3 - l30*y0 - l31*y1 - l32*y2)*i33;
                const float z3 = y3*i33;
                const float z2 = (y2 - l32*z3)*i22;
                const float z1 = (y1 - l21*z2 - l31*z3)*i11;
                const float z0 = (y0 - l10*z1 - l20*z2 - l30*z3)*i00;
                if (lane < 12) {
                    sK[0*12+lane] = -z0; sK[1*12+lane] = -z1;
                    sK[2*12+lane] = -z2; sK[3*12+lane] = -z3;
                } else {
                    skk[0] = -z0; skk[1] = -z1; skk[2] = -z2; skk[3] = -z3;
                }
            }
        }
        wsync();

        // ---- emit K,kk; M = K^T Qux; v' = qx + Qxu kk ----
        if (lane < 52) {
            (Kk + base*52)[lane] = (lane < 48) ? sK[lane] : skk[lane-48];
        }
        if (lane < 36) {
            const int i = lane / 3, jc = (lane % 3) << 2;
            float4 acc = make_float4(0.f,0.f,0.f,0.f);
            #pragma unroll
            for (int m = 0; m < 4; ++m) {
                axpy4(acc, sK[m*12 + i], *(const float4*)(sQ + (12+m)*LDC + jc));
            }
            *(float4*)(sM + i*12 + jc) = acc;
        } else if (lane < 48) {
            const int i = lane - 36;
            float acc = sq[i];
            #pragma unroll
            for (int m = 0; m < 4; ++m) acc += sQ[i*LDC + 12 + m] * skk[m];
            sv[i] = acc;
        }
        wsync();

        // ---- V' = Qxx + 0.5(M + M^T) ----
        if (lane < 36) {
            const int i = lane / 3, jc = (lane % 3) << 2;
            const float4 q  = *(const float4*)(sQ + i*LDC + jc);
            const float4 m1 = *(const float4*)(sM + i*12 + jc);
            const float t0 = sM[(jc+0)*12 + i];
            const float t1 = sM[(jc+1)*12 + i];
            const float t2 = sM[(jc+2)*12 + i];
            const float t3 = sM[(jc+3)*12 + i];
            float4 r;
            r.x = q.x + 0.5f*(m1.x + t0);
            r.y = q.y + 0.5f*(m1.y + t1);
            r.z = q.z + 0.5f*(m1.z + t2);
            r.w = q.w + 0.5f*(m1.w + t3);
            *(float4*)(sV + i*12 + jc) = r;
        }
        cur = nxt;
    }
}

// ---------------------------------------------------------------------------
// Kernel 2: rollout, register-resident redesign. One wave per batch element.
// Lane (a = lane/12, i = lane%12): alpha a, tau component i. Matrix rows in
// registers (global prefetch, vmem pipe); LDS only for tau exchange (~8 DS
// instrs/step vs ~35 before).
// ---------------------------------------------------------------------------
struct Pref {
    float4 C0, C1, C2, C3;   // C row i
    float4 D0, D1, D2, D3;   // C row 12+i   (u-lanes only)
    float4 F0, F1, F2, F3;   // F row i
    float4 K0, K1, K2;       // K row i      (u-lanes only)
    float  kk, ci, c2i, fi;
};

__device__ __forceinline__ Pref pload(
    const float* Cg, const float* cg, const float* Fg, const float* fg,
    const float* Kk, int t, int b, int i, bool ul)
{
    Pref p;
    const size_t base = (size_t)t * B_ + b;
    const float4* Cr = (const float4*)(Cg + base*256 + i*16);
    p.C0 = Cr[0]; p.C1 = Cr[1]; p.C2 = Cr[2]; p.C3 = Cr[3];
    const float4* Fr = (const float4*)(Fg + base*192 + i*16);
    p.F0 = Fr[0]; p.F1 = Fr[1]; p.F2 = Fr[2]; p.F3 = Fr[3];
    p.ci = cg[base*16 + i];
    p.fi = fg[base*12 + i];
    if (ul) {
        const float4* Dr = (const float4*)(Cg + base*256 + (12+i)*16);
        p.D0 = Dr[0]; p.D1 = Dr[1]; p.D2 = Dr[2]; p.D3 = Dr[3];
        const float4* Kr = (const float4*)(Kk + base*52 + i*12);
        p.K0 = Kr[0]; p.K1 = Kr[1]; p.K2 = Kr[2];
        p.kk  = Kk[base*52 + 48 + i];
        p.c2i = cg[base*16 + 12 + i];
    }
    return p;
}

__global__ __launch_bounds__(64) void rollout_kernel(
    const float* __restrict__ x0g, const float* __restrict__ Cg,
    const float* __restrict__ cg,  const float* __restrict__ Fg,
    const float* __restrict__ fg,  const float* __restrict__ Kk,
    float* __restrict__ outg)
{
    const int b    = blockIdx.x;
    const int lane = threadIdx.x;
    int a = lane / 12;
    int i = lane - a*12;
    const bool act = (lane < 60);
    if (!act) { a = 4; i = lane - 52; }       // harmless duplicates (writes masked)
    const bool ulane = act && (i < 4);
    const float alpha = ldexpf(1.0f, -a);     // 0.5^a

    __shared__ __align__(16) float staus[5*AST];   // [a][t][16], a-stride 808
    __shared__ __align__(16) float sunom[T_*NC_];  // [t][4]
    __shared__ __align__(16) float spart[64];
    __shared__ __align__(16) float scost[8];
    __shared__ int sbest;

    const float x0v = x0g[b*12 + i];
    if (lane < 50) *(float4*)(sunom + lane*4) = make_float4(0.f,0.f,0.f,0.f);

    Pref cur = pload(Cg, cg, Fg, fg, Kk, 0, b, i, ulane);
    wsync();

    for (int iter = 0; iter < 3; ++iter) {
        float xv   = x0v;
        float cacc = 0.f;

        for (int t = 0; t < T_; ++t) {
            float* tb = staus + a*AST + t*16;
            // 1. publish my x component
            if (act) tb[i] = xv;
            // prefetch t+1 (wraps to 0: next iteration's first step)
            Pref nxt = pload(Cg, cg, Fg, fg, Kk, (t+1 < T_) ? t+1 : 0, b, i, ulane);
            wsync();
            // 2. read x part (broadcast rows, 2-way banks max)
            const float4 xA = *(const float4*)(tb);
            const float4 xB = *(const float4*)(tb + 4);
            const float4 xC = *(const float4*)(tb + 8);
            // 3. u-lanes compute and publish u
            if (ulane) {
                const float ulqr = dot4f(cur.K0, xA) + dot4f(cur.K1, xB)
                                 + dot4f(cur.K2, xC) + cur.kk;
                const float un = sunom[t*4 + i];
                float u = (1.f - alpha)*un + alpha*ulqr;
                u = fminf(1.f, fmaxf(-1.f, u));
                tb[12 + i] = u;
            }
            wsync();
            // 4. read u part; full tau now in registers
            const float4 uA = *(const float4*)(tb + 12);
            // 5. dots (pure register FMA)
            const float cc = dot4f(cur.C0, xA) + dot4f(cur.C1, xB)
                           + dot4f(cur.C2, xC) + dot4f(cur.C3, uA);
            cacc += (0.5f*cc + cur.ci) * xv;
            if (ulane) {
                const float cc2 = dot4f(cur.D0, xA) + dot4f(cur.D1, xB)
                                + dot4f(cur.D2, xC) + dot4f(cur.D3, uA);
                const float uval = (i == 0) ? uA.x : (i == 1) ? uA.y
                                 : (i == 2) ? uA.z : uA.w;
                cacc += (0.5f*cc2 + cur.c2i) * uval;
            }
            xv = dot4f(cur.F0, xA) + dot4f(cur.F1, xB)
               + dot4f(cur.F2, xC) + dot4f(cur.F3, uA) + cur.fi;
            cur = nxt;
        } // t

        // ---- reduce costs per alpha, first-min argmin (matches jnp.argmin) ----
        spart[lane] = act ? cacc : 0.f;
        wsync();
        if (lane < 5) {
            float s = 0.f;
            #pragma unroll
            for (int j = 0; j < 12; ++j) s += spart[lane*12 + j];
            scost[lane] = s;
        }
        wsync();
        if (lane == 0) {
            int bi = 0; float bc = scost[0];
            #pragma unroll
            for (int aa = 1; aa < 5; ++aa) {
                if (scost[aa] < bc) { bc = scost[aa]; bi = aa; }
            }
            sbest = bi;
        }
        wsync();
        const int best = sbest;

        // ---- u_nom <- best u's; final iter: write best taus to output ----
        if (lane < 50) {
            const float4 uu = *(const float4*)(staus + best*AST + lane*16 + 12);
            *(float4*)(sunom + lane*4) = uu;
        }
        if (iter == 2 && lane < 50) {
            const float* src = staus + best*AST + lane*16;
            float* dst = outg + ((size_t)lane*B_ + b)*16;
            *(float4*)(dst)      = *(const float4*)(src);
            *(float4*)(dst + 4)  = *(const float4*)(src + 4);
            *(float4*)(dst + 8)  = *(const float4*)(src + 8);
            *(float4*)(dst + 12) = *(const float4*)(src + 12);
        }
        wsync();
    } // iter
}

extern "C" void kernel_launch(void* const* d_in, const int* in_sizes, int n_in,
                              void* d_out, int out_size, void* d_ws, size_t ws_size,
                              hipStream_t stream) {
    const float* x0 = (const float*)d_in[0];
    const float* C  = (const float*)d_in[1];
    const float* c  = (const float*)d_in[2];
    const float* F  = (const float*)d_in[3];
    const float* f  = (const float*)d_in[4];
    float* out = (float*)d_out;
    float* Kk  = (float*)d_ws;   // 50*2048*52*4 = 21.3 MB

    riccati_kernel<<<B_, 64, 0, stream>>>(C, c, F, f, Kk);
    rollout_kernel<<<B_, 64, 0, stream>>>(x0, C, c, F, f, Kk, out);
}

// Round 4
// 464.930 us; speedup vs baseline: 1.0270x; 1.0270x over previous
//
#include <hip/hip_runtime.h>
#include <math.h>

#define T_   50
#define B_   2048
#define NS_  12
#define NC_  4
#define NSC_ 16
#define LDC  20     // padded LDS row stride for 16-wide matrices
#define AST  808    // per-alpha stride for tau trajectories (50*16=800, +8 bank skew)

__device__ __forceinline__ float dot4f(const float4 a, const float4 b) {
    return a.x*b.x + a.y*b.y + a.z*b.z + a.w*b.w;
}
__device__ __forceinline__ void axpy4(float4& acc, float s, const float4 v) {
    acc.x += s*v.x; acc.y += s*v.y; acc.z += s*v.z; acc.w += s*v.w;
}

// Wave-local sync for single-wave blocks: orders LDS write->read (lgkmcnt(0))
// WITHOUT draining vmcnt, so global prefetch loads stay in flight.
__device__ __forceinline__ void wsync() {
    __builtin_amdgcn_wave_barrier();
    __builtin_amdgcn_s_waitcnt(0xC07F);   // vmcnt(63) expcnt(7) lgkmcnt(0)
    __builtin_amdgcn_wave_barrier();
}

// Quad (4-lane) sum via DPP quad_perm — VALU pipe, zero DS-pipe cost.
__device__ __forceinline__ float qsum(float v) {
    v += __int_as_float(__builtin_amdgcn_update_dpp(
            0, __float_as_int(v), 0xB1, 0xF, 0xF, true));  // xor 1: [1,0,3,2]
    v += __int_as_float(__builtin_amdgcn_update_dpp(
            0, __float_as_int(v), 0x4E, 0xF, 0xF, true));  // xor 2: [2,3,0,1]
    return v;
}

// ---------------------------------------------------------------------------
// Kernel 1: backward Riccati. One wave per batch element. DS-instr-minimized:
// F^T staged (kills 12x b32 column reads), Quu rows read b128, K stored
// transposed (1 b128 solve write, 1 b128 M-phase read), qu in Q pad col 16.
// ---------------------------------------------------------------------------
struct RicPref { float4 rC, rAux; };

__device__ __forceinline__ RicPref ric_load(
    const float* Cg, const float* cg, const float* Fg, const float* fg,
    int t, int b, int lane)
{
    RicPref p;
    const size_t base = (size_t)t * B_ + b;
    p.rC = ((const float4*)(Cg + base*256))[lane];
    if (lane < 48)      p.rAux = ((const float4*)(Fg + base*192))[lane];
    else if (lane < 52) p.rAux = ((const float4*)(cg + base*16))[lane-48];
    else if (lane < 55) p.rAux = ((const float4*)(fg + base*12))[lane-52];
    return p;
}

__global__ __launch_bounds__(64) void riccati_kernel(
    const float* __restrict__ Cg, const float* __restrict__ cg,
    const float* __restrict__ Fg, const float* __restrict__ fg,
    float* __restrict__ Kk)
{
    const int b    = blockIdx.x;
    const int lane = threadIdx.x;

    __shared__ __align__(16) float sV[144];      // V 12x12 (stride 12)
    __shared__ __align__(16) float sv[12];
    __shared__ __align__(16) float sF[12*LDC];   // F 12x16 (stride 20)
    __shared__ __align__(16) float sFT[16*12];   // F^T 16x12 (row j = F[:,j])
    __shared__ __align__(16) float sc[16];
    __shared__ __align__(16) float sf[12];
    __shared__ __align__(16) float sP[12*LDC];   // P = V*F
    __shared__ __align__(16) float sQ[16*LDC];   // Q 16x16; col 16 = qu (rows 12..15)
    __shared__ __align__(16) float sq[16];
    __shared__ __align__(16) float stmp[12];     // V f + v
    __shared__ __align__(16) float sKT[56];      // [c][m] = K[m][c]; c=12 -> kk
    __shared__ __align__(16) float sM[144];      // M = K^T Qux (stride 12)

    for (int i = lane; i < 144; i += 64) sV[i] = 0.f;
    if (lane < 12) sv[lane] = 0.f;

    RicPref cur = ric_load(Cg, cg, Fg, fg, T_-1, b, lane);
    wsync();

    for (int t = T_ - 1; t >= 0; --t) {
        const size_t base = (size_t)t * B_ + b;

        // ---- stage F, F^T, c, f (C stays in registers) ----
        wsync();   // WAR vs prior step's readers
        const float4 rCq = cur.rC;
        {
            const int row = lane >> 2, chx = lane & 3;
            if (lane < 48) {
                *(float4*)(sF + row*LDC + (chx<<2)) = cur.rAux;
                sFT[(4*chx+0)*12 + row] = cur.rAux.x;
                sFT[(4*chx+1)*12 + row] = cur.rAux.y;
                sFT[(4*chx+2)*12 + row] = cur.rAux.z;
                sFT[(4*chx+3)*12 + row] = cur.rAux.w;
            }
            else if (lane < 52) ((float4*)sc)[lane-48] = cur.rAux;
            else if (lane < 55) ((float4*)sf)[lane-52] = cur.rAux;
        }
        RicPref nxt = ric_load(Cg, cg, Fg, fg, (t > 0) ? t-1 : 0, b, lane);
        wsync();

        // ---- P = V*F (12x16); tmp = V f + v (jc==0 lanes, b128 f reads) ----
        if (lane < 48) {
            const int k = lane >> 2, jc = (lane & 3) << 2;
            const float4 v0 = *(const float4*)(sV + k*12);
            const float4 v1 = *(const float4*)(sV + k*12 + 4);
            const float4 v2 = *(const float4*)(sV + k*12 + 8);
            const float vk[12] = {v0.x,v0.y,v0.z,v0.w, v1.x,v1.y,v1.z,v1.w,
                                  v2.x,v2.y,v2.z,v2.w};
            float4 acc = make_float4(0.f,0.f,0.f,0.f);
            #pragma unroll
            for (int l = 0; l < 12; ++l)
                axpy4(acc, vk[l], *(const float4*)(sF + l*LDC + jc));
            *(float4*)(sP + k*LDC + jc) = acc;
            if (jc == 0) {
                float accT = sv[k]
                    + dot4f(v0, *(const float4*)(sf))
                    + dot4f(v1, *(const float4*)(sf+4))
                    + dot4f(v2, *(const float4*)(sf+8));
                stmp[k] = accT;
            }
        }
        wsync();

        // ---- Q = C + F^T P; q = c + F^T tmp (b128 sFT/stmp reads) ----
        {
            const int i = lane >> 2, jc = (lane & 3) << 2;
            const float4 f0 = *(const float4*)(sFT + i*12);
            const float4 f1 = *(const float4*)(sFT + i*12 + 4);
            const float4 f2 = *(const float4*)(sFT + i*12 + 8);
            const float fcol[12] = {f0.x,f0.y,f0.z,f0.w, f1.x,f1.y,f1.z,f1.w,
                                    f2.x,f2.y,f2.z,f2.w};
            float4 acc = rCq;
            #pragma unroll
            for (int k = 0; k < 12; ++k)
                axpy4(acc, fcol[k], *(const float4*)(sP + k*LDC + jc));
            *(float4*)(sQ + i*LDC + jc) = acc;
            if (jc == 0) {
                const float accq = sc[i]
                    + dot4f(f0, *(const float4*)(stmp))
                    + dot4f(f1, *(const float4*)(stmp+4))
                    + dot4f(f2, *(const float4*)(stmp+8));
                sq[i] = accq;
                if (i >= 12) sQ[i*LDC + 16] = accq;   // qu into pad column
            }
        }
        wsync();

        // ---- solve Quu sol = [Qux | qu] (redundant Cholesky, b128 reads) ----
        {
            const float4 u0 = *(const float4*)(sQ + 12*LDC + 12);
            const float4 u1 = *(const float4*)(sQ + 13*LDC + 12);
            const float4 u2 = *(const float4*)(sQ + 14*LDC + 12);
            const float4 u3 = *(const float4*)(sQ + 15*LDC + 12);
            const float l00 = sqrtf(u0.x), i00 = 1.f/l00;
            const float l10 = u0.y*i00, l20 = u0.z*i00, l30 = u0.w*i00;
            const float l11 = sqrtf(u1.y - l10*l10), i11 = 1.f/l11;
            const float l21 = (u1.z - l20*l10)*i11;
            const float l31 = (u1.w - l30*l10)*i11;
            const float l22 = sqrtf(u2.z - l20*l20 - l21*l21), i22 = 1.f/l22;
            const float l32 = (u2.w - l30*l20 - l31*l21)*i22;
            const float l33 = sqrtf(u3.w - l30*l30 - l31*l31 - l32*l32), i33 = 1.f/l33;
            if (lane < 13) {
                const int cidx = (lane < 12) ? lane : 16;
                const float r0 = sQ[12*LDC + cidx];
                const float r1 = sQ[13*LDC + cidx];
                const float r2 = sQ[14*LDC + cidx];
                const float r3 = sQ[15*LDC + cidx];
                const float y0 = r0*i00;
                const float y1 = (r1 - l10*y0)*i11;
                const float y2 = (r2 - l20*y0 - l21*y1)*i22;
                const float y3 = (r3 - l30*y0 - l31*y1 - l32*y2)*i33;
                const float z3 = y3*i33;
                const float z2 = (y2 - l32*z3)*i22;
                const float z1 = (y1 - l21*z2 - l31*z3)*i11;
                const float z0 = (y0 - l10*z1 - l20*z2 - l30*z3)*i00;
                *(float4*)(sKT + lane*4) = make_float4(-z0,-z1,-z2,-z3);
            }
        }
        wsync();

        // ---- emit K (row-major) + kk; M = K^T Qux; v' = qx + Qxu kk ----
        if (lane < 52) {
            float val;
            if (lane < 48) {
                const int i2 = lane / 12, j2 = lane - i2*12;
                val = sKT[j2*4 + i2];
            } else val = sKT[lane];
            (Kk + base*52)[lane] = val;
        }
        if (lane < 36) {
            const int i = lane / 3, jc = (lane % 3) << 2;
            const float4 kv = *(const float4*)(sKT + i*4);   // K[0..3][i]
            float4 acc = make_float4(0.f,0.f,0.f,0.f);
            axpy4(acc, kv.x, *(const float4*)(sQ + 12*LDC + jc));
            axpy4(acc, kv.y, *(const float4*)(sQ + 13*LDC + jc));
            axpy4(acc, kv.z, *(const float4*)(sQ + 14*LDC + jc));
            axpy4(acc, kv.w, *(const float4*)(sQ + 15*LDC + jc));
            *(float4*)(sM + i*12 + jc) = acc;
        } else if (lane < 48) {
            const int i = lane - 36;
            const float4 qxu = *(const float4*)(sQ + i*LDC + 12);
            const float4 kk4 = *(const float4*)(sKT + 48);
            sv[i] = sq[i] + dot4f(qxu, kk4);
        }
        wsync();

        // ---- V' = Qxx + 0.5(M + M^T) ----
        if (lane < 36) {
            const int i = lane / 3, jc = (lane % 3) << 2;
            const float4 q  = *(const float4*)(sQ + i*LDC + jc);
            const float4 m1 = *(const float4*)(sM + i*12 + jc);
            const float t0 = sM[(jc+0)*12 + i];
            const float t1 = sM[(jc+1)*12 + i];
            const float t2 = sM[(jc+2)*12 + i];
            const float t3 = sM[(jc+3)*12 + i];
            float4 rr;
            rr.x = q.x + 0.5f*(m1.x + t0);
            rr.y = q.y + 0.5f*(m1.y + t1);
            rr.z = q.z + 0.5f*(m1.z + t2);
            rr.w = q.w + 0.5f*(m1.w + t3);
            *(float4*)(sV + i*12 + jc) = rr;
        }
        cur = nxt;
    }
}

// ---------------------------------------------------------------------------
// Kernel 2: rollout. Lane (r=lane>>2, ch=lane&3) keeps C/F row-chunks in
// registers straight from coalesced staging loads. 17 DS instrs/step:
// u-phase 5, tau-chunk reads 5, hi-lane tau_r 5, x' publish 2.
// Cost partials accumulate in registers; one shuffle-reduce per iteration.
// ---------------------------------------------------------------------------
struct RP { float4 C, F, K0, K1, K2; float kk, cr, fr; };

__device__ __forceinline__ RP rp_load(
    const float* __restrict__ Cg, const float* __restrict__ cg,
    const float* __restrict__ Fg, const float* __restrict__ fg,
    const float* __restrict__ Kg, int t, int b, int lane, int r)
{
    RP p;
    const size_t base = (size_t)t * B_ + b;
    p.C  = ((const float4*)(Cg + base*256))[lane];     // C[r][4ch..]
    p.cr = cg[base*16 + r];
    if (lane < 48) {
        p.F  = ((const float4*)(Fg + base*192))[lane]; // F[r][4ch..]
        p.fr = fg[base*12 + r];
    }
    if (lane < 20) {                                   // u-lane: a=r, i=ch
        const float* Kr = Kg + base*52 + (lane & 3)*12;
        p.K0 = *(const float4*)(Kr);
        p.K1 = *(const float4*)(Kr + 4);
        p.K2 = *(const float4*)(Kr + 8);
        p.kk = Kg[base*52 + 48 + (lane & 3)];
    }
    return p;
}

__global__ __launch_bounds__(64) void rollout_kernel(
    const float* __restrict__ x0g, const float* __restrict__ Cg,
    const float* __restrict__ cg,  const float* __restrict__ Fg,
    const float* __restrict__ fg,  const float* __restrict__ Kk,
    float* __restrict__ outg)
{
    const int b    = blockIdx.x;
    const int lane = threadIdx.x;
    const int r  = lane >> 2, ch = lane & 3;
    const bool lo = (lane < 48);                       // r < 12
    const float alpha_u = ldexpf(1.f, -r);             // u-lane alpha (lanes<20)

    __shared__ __align__(16) float staus[5*AST + 16];  // [a][t][16]
    __shared__ __align__(16) float sunom[T_*NC_];      // [t][4]

    float x0v = 0.f;
    if (lo) x0v = x0g[b*12 + r];
    if (lane < 50) *(float4*)(sunom + lane*4) = make_float4(0.f,0.f,0.f,0.f);

    RP cur = rp_load(Cg, cg, Fg, fg, Kk, 0, b, lane, r);
    wsync();

    for (int iter = 0; iter < 3; ++iter) {
        float tau_r[5], cacc[5], xnew[5];
        #pragma unroll
        for (int a = 0; a < 5; ++a) { tau_r[a] = x0v; cacc[a] = 0.f; }
        if (lo) {                                      // publish x0 -> staus[*][0]
            staus[ch*AST + r] = x0v;
            if (ch == 0) staus[4*AST + r] = x0v;
        }

        for (int t = 0; t < T_; ++t) {
            wsync();   // prior x'/init/unom writes -> this step's reads
            // ---- u phase (lanes 0..19) ----
            if (lane < 20) {
                const float* xb = staus + r*AST + t*16;
                const float4 xA = *(const float4*)(xb);
                const float4 xB = *(const float4*)(xb + 4);
                const float4 xC = *(const float4*)(xb + 8);
                const float ulqr = dot4f(cur.K0, xA) + dot4f(cur.K1, xB)
                                 + dot4f(cur.K2, xC) + cur.kk;
                float u = (1.f - alpha_u)*sunom[t*4 + ch] + alpha_u*ulqr;
                u = fminf(1.f, fmaxf(-1.f, u));
                staus[r*AST + t*16 + 12 + ch] = u;
            }
            RP nxt = rp_load(Cg, cg, Fg, fg, Kk, (t+1 < T_) ? t+1 : 0, b, lane, r);
            wsync();   // u write -> tau reads
            // ---- cost partials + x' update (chunk reads shared) ----
            #pragma unroll
            for (int a = 0; a < 5; ++a) {
                const float4 c4 = *(const float4*)(staus + a*AST + t*16 + (ch<<2));
                if (!lo) tau_r[a] = staus[a*AST + t*16 + r];   // u components
                float contrib = 0.5f * dot4f(cur.C, c4);
                if (ch == 0) contrib += cur.cr;
                cacc[a] += contrib * tau_r[a];
                if (lo) xnew[a] = qsum(dot4f(cur.F, c4)) + cur.fr;
            }
            if (lo) {
                staus[ch*AST + (t+1)*16 + r] = xnew[ch];
                if (ch == 0) staus[4*AST + (t+1)*16 + r] = xnew[4];
                #pragma unroll
                for (int a = 0; a < 5; ++a) tau_r[a] = xnew[a];
            }
            cur = nxt;
        } // t

        wsync();
        // ---- reduce costs across 64 lanes; redundant first-min argmin ----
        #pragma unroll
        for (int a = 0; a < 5; ++a) {
            float v = cacc[a];
            #pragma unroll
            for (int off = 1; off < 64; off <<= 1) v += __shfl_xor(v, off, 64);
            cacc[a] = v;
        }
        int best = 0; float bc = cacc[0];
        #pragma unroll
        for (int a = 1; a < 5; ++a)
            if (cacc[a] < bc) { bc = cacc[a]; best = a; }

        // ---- u_nom <- best u; final iter: write best taus out ----
        if (lane < 50)
            *(float4*)(sunom + lane*4) =
                *(const float4*)(staus + best*AST + lane*16 + 12);
        if (iter == 2 && lane < 50) {
            const float* src = staus + best*AST + lane*16;
            float* dst = outg + ((size_t)lane*B_ + b)*16;
            *(float4*)(dst)      = *(const float4*)(src);
            *(float4*)(dst + 4)  = *(const float4*)(src + 4);
            *(float4*)(dst + 8)  = *(const float4*)(src + 8);
            *(float4*)(dst + 12) = *(const float4*)(src + 12);
        }
    } // iter
}

extern "C" void kernel_launch(void* const* d_in, const int* in_sizes, int n_in,
                              void* d_out, int out_size, void* d_ws, size_t ws_size,
                              hipStream_t stream) {
    const float* x0 = (const float*)d_in[0];
    const float* C  = (const float*)d_in[1];
    const float* c  = (const float*)d_in[2];
    const float* F  = (const float*)d_in[3];
    const float* f  = (const float*)d_in[4];
    float* out = (float*)d_out;
    float* Kk  = (float*)d_ws;   // 50*2048*52*4 = 21.3 MB

    riccati_kernel<<<B_, 64, 0, stream>>>(C, c, F, f, Kk);
    rollout_kernel<<<B_, 64, 0, stream>>>(x0, C, c, F, f, Kk, out);
}